// Round 6
// baseline (585.066 us; speedup 1.0000x reference)
//
#include <hip/hip_runtime.h>
#include <math.h>

typedef __bf16 bf16_t;
typedef __bf16 bf16x8 __attribute__((ext_vector_type(8)));
typedef float f32x4 __attribute__((ext_vector_type(4)));

// async global->LDS, 16B per lane; LDS dest is wave-uniform base + lane*16
#define LDS16(g, l) __builtin_amdgcn_global_load_lds( \
    (__attribute__((address_space(1))) void*)(g),     \
    (__attribute__((address_space(3))) void*)(l), 16, 0, 0)

// ---------------------------------------------------------------------------
// Prep kernel: blocks [0,11264) fp32->bf16 flat weight cvt;
// [11264,12288) out_proj^T (32x32 tiles); [12288,20480) rmsnorm(x)*ln1 -> h1
// ---------------------------------------------------------------------------
__global__ __launch_bounds__(256) void prep_kernel(
    const float* __restrict__ qp, const float* __restrict__ kp,
    const float* __restrict__ vp, const float* __restrict__ f1,
    const float* __restrict__ f2, const float* __restrict__ op,
    const float* __restrict__ x, const float* __restrict__ ln1,
    bf16_t* __restrict__ qkvb, bf16_t* __restrict__ f1b,
    bf16_t* __restrict__ f2b, bf16_t* __restrict__ opT,
    bf16_t* __restrict__ h1)
{
    __shared__ float tile[32][33];
    __shared__ float red[4];
    int bid = blockIdx.x;
    int t = threadIdx.x;
    if (bid < 11264) {
        size_t i = ((size_t)bid * 256 + t) * 4;
        const float* src;
        bf16_t* dst;
        if (i < 3145728) {
            if (i < 1048576)      { src = qp + i;             dst = qkvb + i; }
            else if (i < 2097152) { src = kp + (i - 1048576); dst = qkvb + i; }
            else                  { src = vp + (i - 2097152); dst = qkvb + i; }
        } else if (i < 7340032) { src = f1 + (i - 3145728); dst = f1b + (i - 3145728); }
        else                    { src = f2 + (i - 7340032); dst = f2b + (i - 7340032); }
        float4 v = *(const float4*)src;
        dst[0] = (bf16_t)v.x; dst[1] = (bf16_t)v.y;
        dst[2] = (bf16_t)v.z; dst[3] = (bf16_t)v.w;
    } else if (bid < 12288) {
        int b2 = bid - 11264;
        int c0 = (b2 & 31) * 32, r0 = (b2 >> 5) * 32;
        int tx = t & 31, ty = t >> 5;  // 32 x 8
#pragma unroll
        for (int i = 0; i < 32; i += 8)
            tile[ty + i][tx] = op[(size_t)(r0 + ty + i) * 1024 + c0 + tx];
        __syncthreads();
#pragma unroll
        for (int i = 0; i < 32; i += 8)
            opT[(size_t)(c0 + ty + i) * 1024 + r0 + tx] = (bf16_t)tile[tx][ty + i];
    } else {
        int row = bid - 12288;
        float4 xv = ((const float4*)(x + (size_t)row * 1024))[t];
        float ss = xv.x * xv.x + xv.y * xv.y + xv.z * xv.z + xv.w * xv.w;
#pragma unroll
        for (int o = 32; o > 0; o >>= 1) ss += __shfl_xor(ss, o, 64);
        if ((t & 63) == 0) red[t >> 6] = ss;
        __syncthreads();
        ss = red[0] + red[1] + red[2] + red[3];
        float rinv = rsqrtf(ss * (1.0f / 1024.0f) + 1e-5f);
        float4 wv = ((const float4*)ln1)[t];
        bf16_t* hp = h1 + (size_t)row * 1024 + t * 4;
        hp[0] = (bf16_t)(xv.x * rinv * wv.x);
        hp[1] = (bf16_t)(xv.y * rinv * wv.y);
        hp[2] = (bf16_t)(xv.z * rinv * wv.z);
        hp[3] = (bf16_t)(xv.w * rinv * wv.w);
    }
}

// ---------------------------------------------------------------------------
// RMSNorm standalone (for h2): fp32 x in, bf16 h = x/rms(x)*w
// ---------------------------------------------------------------------------
__global__ __launch_bounds__(256) void rmsnorm_kernel(
    const float* __restrict__ x, const float* __restrict__ w,
    bf16_t* __restrict__ h)
{
    int row = blockIdx.x;
    int t = threadIdx.x;
    float4 xv = ((const float4*)(x + (size_t)row * 1024))[t];
    float ss = xv.x * xv.x + xv.y * xv.y + xv.z * xv.z + xv.w * xv.w;
#pragma unroll
    for (int o = 32; o > 0; o >>= 1) ss += __shfl_xor(ss, o, 64);
    __shared__ float red[4];
    if ((t & 63) == 0) red[t >> 6] = ss;
    __syncthreads();
    ss = red[0] + red[1] + red[2] + red[3];
    float rinv = rsqrtf(ss * (1.0f / 1024.0f) + 1e-5f);
    float4 wv = ((const float4*)w)[t];
    bf16_t* hp = h + (size_t)row * 1024 + t * 4;
    hp[0] = (bf16_t)(xv.x * rinv * wv.x);
    hp[1] = (bf16_t)(xv.y * rinv * wv.y);
    hp[2] = (bf16_t)(xv.z * rinv * wv.z);
    hp[3] = (bf16_t)(xv.w * rinv * wv.w);
}

// ---------------------------------------------------------------------------
// bf16 batched transpose with input row stride: out[c][r] = in[r*ldin + c]
// ---------------------------------------------------------------------------
__global__ __launch_bounds__(256) void transpose_bf16(
    const bf16_t* __restrict__ in, bf16_t* __restrict__ out,
    int rows, int ldin, long long sIn, long long sOut)
{
    __shared__ bf16_t tile[32][33];
    int b = blockIdx.z;
    const bf16_t* ip = in + (long long)b * sIn;
    bf16_t* op = out + (long long)b * sOut;
    int c0 = blockIdx.x * 32, r0 = blockIdx.y * 32;
    int tx = threadIdx.x & 31, ty = threadIdx.x >> 5;
#pragma unroll
    for (int i = 0; i < 32; i += 8)
        tile[ty + i][tx] = ip[(size_t)(r0 + ty + i) * ldin + c0 + tx];
    __syncthreads();
#pragma unroll
    for (int i = 0; i < 32; i += 8)
        op[(size_t)(c0 + ty + i) * rows + r0 + tx] = tile[tx][ty + i];
}

// ---------------------------------------------------------------------------
// Causal softmax, in place, vectorized. Row q: softmax over cols [0,q];
// writes zeros on (q, Jstore) where Jstore = next 128-boundary (all AV-gemm
// ever reads, due to its K-clamp). Cols >= Jstore left untouched.
// ---------------------------------------------------------------------------
__global__ __launch_bounds__(256) void causal_softmax_kernel(bf16_t* __restrict__ SP)
{
    const int S = 2048;
    int q = blockIdx.x, b = blockIdx.y;
    bf16_t* row = SP + ((size_t)b * S + q) * S;
    int t = threadIdx.x;
    int j0 = t * 8;
    int Jstore = ((q >> 7) + 1) << 7;

    float v[8];
    if (j0 + 7 <= q) {
        bf16x8 xv = *(const bf16x8*)(row + j0);
#pragma unroll
        for (int i = 0; i < 8; i++) v[i] = (float)xv[i];
    } else if (j0 <= q) {
#pragma unroll
        for (int i = 0; i < 8; i++)
            v[i] = (j0 + i <= q) ? (float)row[j0 + i] : -1e30f;
    } else {
#pragma unroll
        for (int i = 0; i < 8; i++) v[i] = -1e30f;
    }

    float mx = v[0];
#pragma unroll
    for (int i = 1; i < 8; i++) mx = fmaxf(mx, v[i]);
#pragma unroll
    for (int o = 32; o > 0; o >>= 1) mx = fmaxf(mx, __shfl_xor(mx, o, 64));
    __shared__ float sm[4], ssum[4];
    if ((t & 63) == 0) sm[t >> 6] = mx;
    __syncthreads();
    mx = fmaxf(fmaxf(sm[0], sm[1]), fmaxf(sm[2], sm[3]));

    float e[8];
    float sum = 0.f;
#pragma unroll
    for (int i = 0; i < 8; i++) {
        e[i] = (v[i] > -1e29f) ? expf(v[i] - mx) : 0.f;
        sum += e[i];
    }
#pragma unroll
    for (int o = 32; o > 0; o >>= 1) sum += __shfl_xor(sum, o, 64);
    if ((t & 63) == 0) ssum[t >> 6] = sum;
    __syncthreads();
    sum = ssum[0] + ssum[1] + ssum[2] + ssum[3];
    float r = 1.0f / sum;

    if (j0 < Jstore) {
        bf16x8 ov;
#pragma unroll
        for (int i = 0; i < 8; i++) ov[i] = (bf16_t)(e[i] * r);
        *(bf16x8*)(row + j0) = ov;
    }
}

// ---------------------------------------------------------------------------
// P0 += P1 combine for split-K (fp32, float4 grid-stride)
// ---------------------------------------------------------------------------
__global__ __launch_bounds__(256) void addp_kernel(
    float* __restrict__ out, const float* __restrict__ p1, int n4)
{
    int i = blockIdx.x * 256 + threadIdx.x;
    int stride = gridDim.x * 256;
    for (; i < n4; i += stride) {
        float4 a = ((const float4*)out)[i];
        float4 b = ((const float4*)p1)[i];
        a.x += b.x; a.y += b.y; a.z += b.z; a.w += b.w;
        ((float4*)out)[i] = a;
    }
}

// ---------------------------------------------------------------------------
// MFMA GEMM (legacy 128x128, 2-barrier): kept for causal scores (CSKIP) and
// AV (CKLOOP) and the small-ws FFN fallback. See gemm256 for the hot path.
// ---------------------------------------------------------------------------
template <int EPI, bool CSKIP, bool CKLOOP, bool ASPLIT>
__global__ __launch_bounds__(256) void gemm_bt(
    const bf16_t* __restrict__ A, const bf16_t* __restrict__ A2, int lda,
    const bf16_t* __restrict__ B, int ldb,
    void* Cv, int ldc, const float* R,
    int K, int Ksp, int Mt, long long sA, long long sB, long long sC,
    float scale)
{
    int id = blockIdx.x, bz = blockIdx.z;
    int xcd = id & 7, p = id >> 3;
    int chunk = Mt >> 3;
    int bm = xcd * chunk + (p % chunk);
    int bn = p / chunk;
    if (CSKIP && bn > bm) return;

    __shared__ __align__(16) bf16_t At[128 * 64];
    __shared__ __align__(16) bf16_t Bt[128 * 64];
    int t = threadIdx.x;
    int w = t >> 6, l = t & 63;
    int wm = w >> 1, wn = w & 1;
    int lane_m = l & 15, quad = l >> 4;

    const bf16_t* Ag = A + (long long)bz * sA + (size_t)(bm * 128) * lda;
    const bf16_t* Bg = B + (long long)bz * sB + (size_t)(bn * 128) * ldb;

    int Keff = K;
    if (CKLOOP) {
        int kk = (bm + 1) * 128;
        if (kk < K) Keff = kk;
    }

    f32x4 acc[4][4] = {};

    int rb = w * 8 + (l >> 3);
    int g0 = ((l & 7) ^ ((l >> 3) & 7)) * 8;
    const bf16_t* a0[4];
    const bf16_t* a1[4];
    const bf16_t* b0[4];
#pragma unroll
    for (int j = 0; j < 4; j++) {
        size_t ro = (size_t)(rb + 32 * j);
        a0[j] = Ag + ro * lda + g0;
        if (ASPLIT) a1[j] = A2 + (long long)bz * sA + (size_t)(bm * 128) * lda
                           + ro * lda + g0;
        b0[j] = Bg + ro * ldb + g0;
    }

    int s0 = (quad ^ (lane_m & 7)) * 8;        // k-half 0: g = quad
    int s1 = ((4 + quad) ^ (lane_m & 7)) * 8;  // k-half 1: g = 4+quad

    for (int kt = 0; kt < Keff; kt += 64) {
        __syncthreads();
#pragma unroll
        for (int j = 0; j < 4; j++) {
            const bf16_t* pa = a0[j] + kt;
            if (ASPLIT && kt >= Ksp) pa = a1[j] + (kt - Ksp);
            LDS16(pa, At + (size_t)w * 512 + j * 2048);
            LDS16(b0[j] + kt, Bt + (size_t)w * 512 + j * 2048);
        }
        __syncthreads();

#pragma unroll
        for (int h = 0; h < 2; h++) {
            int sh = h ? s1 : s0;
            bf16x8 af[4], bfr[4];
#pragma unroll
            for (int mi = 0; mi < 4; mi++)
                af[mi] = *(const bf16x8*)(At + (wm * 64 + mi * 16 + lane_m) * 64 + sh);
#pragma unroll
            for (int ni = 0; ni < 4; ni++)
                bfr[ni] = *(const bf16x8*)(Bt + (wn * 64 + ni * 16 + lane_m) * 64 + sh);
#pragma unroll
            for (int mi = 0; mi < 4; mi++)
#pragma unroll
                for (int ni = 0; ni < 4; ni++)
                    acc[mi][ni] = __builtin_amdgcn_mfma_f32_16x16x32_bf16(
                        af[mi], bfr[ni], acc[mi][ni], 0, 0, 0);
        }
    }

    long long cbase = (long long)bz * sC;
#pragma unroll
    for (int mi = 0; mi < 4; mi++) {
#pragma unroll
        for (int r = 0; r < 4; r++) {
            int row = bm * 128 + wm * 64 + mi * 16 + quad * 4 + r;
#pragma unroll
            for (int ni = 0; ni < 4; ni++) {
                int col = bn * 128 + wn * 64 + ni * 16 + lane_m;
                float v = acc[mi][ni][r];
                size_t idx = (size_t)(cbase + (long long)row * ldc + col);
                if (EPI == 0) {
                    ((bf16_t*)Cv)[idx] = (bf16_t)(v * scale);
                } else if (EPI == 1) {
                    float g = 0.5f * v * (1.0f + erff(v * 0.70710678118654752f));
                    ((bf16_t*)Cv)[idx] = (bf16_t)g;
                } else {
                    float rv = R[(size_t)row * ldc + col];
                    ((float*)Cv)[idx] = v + rv;
                }
            }
        }
    }
}

// ---------------------------------------------------------------------------
// gemm256: 8-phase pipelined GEMM, C[M,N] = A * B^T (+epilogue).
// BM=BN=256, BK=64, 512 thr = 8 waves (2M x 4N), wave tile 128x64.
// LDS 128 KiB: As/Bs[buf][khalf][256 rows][4 slots x 8].
// Swizzle (proven r5, conflicts=0): slot = g ^ ((row>>1)&3).
//
// r6 PIPELINED PHASES (one barrier/phase, counted lgkm):
// phase p = {issue ds_reads for p+1's fragments (4 A, +4 B on even p);
//   issue stage (2 gload_lds); s_waitcnt lgkmcnt(just-issued) -> retires p's
//   own fragments (read during p-1); sched_barrier(0); setprio(1); 16 MFMA;
//   setprio(0); [odd p: vmcnt(6)]; s_barrier}.
// Next-phase LDS reads drain in the LDS pipe WHILE MFMA runs (previous
// 2-barrier structure serialized read-section and MFMA-section -> 29% Mfma).
// Fragment regs double-buffered: af0/af1 per-phase, bfr0/bfr1 per phase-pair.
//
// vmcnt(6) FIFO ledger (steady): ph1 retires prev ph5/6 stages (buf0k1),
// ph3 retires prev ph7/8 (buf1k0), ph5 retires ph1/2 (buf1k1), ph7 retires
// ph3/4 (next buf0k0) -- each one phase+barrier before its dependent reads.
// Peeled last iter: waits 6/4/0 at ph1/3/5. Write-after-read separation is
// >= 2 phases+barriers for every buffer half (reads retired by lgkm at p+1,
// re-staged earliest at p+3).
// EPI 3 = split-K over blockIdx.y (s0: Cv=v+R, s1: C2=v; addp combines).
// ---------------------------------------------------------------------------
#define VM6 asm volatile("s_waitcnt vmcnt(6)" ::: "memory")
#define VM4 asm volatile("s_waitcnt vmcnt(4)" ::: "memory")
#define VM0 asm volatile("s_waitcnt vmcnt(0)" ::: "memory")
#define NOP ((void)0)

#define STAGE_A(BUF, KH, KOFF) do { \
    LDS16(rA0 + (KOFF), &As[BUF][KH][w * 512]);        \
    LDS16(rA1 + (KOFF), &As[BUF][KH][4096 + w * 512]); } while (0)
#define STAGE_B(BUF, KH, KOFF) do { \
    LDS16(rB0 + (KOFF), &Bs[BUF][KH][w * 512]);        \
    LDS16(rB1 + (KOFF), &Bs[BUF][KH][4096 + w * 512]); } while (0)

// next-phase fragment reads (explicitly unrolled; static indices)
#define RD_A(DST, BUF, KH, MQ) do {                                     \
    DST[0] = *(const bf16x8*)&As[BUF][KH][arow + (MQ)*2048 + 0*512];    \
    DST[1] = *(const bf16x8*)&As[BUF][KH][arow + (MQ)*2048 + 1*512];    \
    DST[2] = *(const bf16x8*)&As[BUF][KH][arow + (MQ)*2048 + 2*512];    \
    DST[3] = *(const bf16x8*)&As[BUF][KH][arow + (MQ)*2048 + 3*512]; } while (0)
#define RD_B(DST, BUF, KH) do {                                         \
    DST[0] = *(const bf16x8*)&Bs[BUF][KH][brow + 0*512];                \
    DST[1] = *(const bf16x8*)&Bs[BUF][KH][brow + 1*512];                \
    DST[2] = *(const bf16x8*)&Bs[BUF][KH][brow + 2*512];                \
    DST[3] = *(const bf16x8*)&Bs[BUF][KH][brow + 3*512]; } while (0)

// AFC/BFC: current fragments (read in prev phase); NRD: next-phase reads;
// LGK: literal = count of reads NRD issues; MQ: current acc row half.
#define PHASE(AFC, BFC, MQ, NRD_STMT, LGK, STAGE_STMT, VMW_STMT)              \
  {                                                                           \
    NRD_STMT;                                                                 \
    STAGE_STMT;                                                               \
    asm volatile("s_waitcnt lgkmcnt(" #LGK ")" ::: "memory");                 \
    __builtin_amdgcn_sched_barrier(0);                                        \
    __builtin_amdgcn_s_setprio(1);                                            \
    _Pragma("unroll") for (int mi = 0; mi < 4; mi++)                          \
      _Pragma("unroll") for (int ni = 0; ni < 4; ni++)                        \
        acc[(MQ)*4 + mi][ni] = __builtin_amdgcn_mfma_f32_16x16x32_bf16(       \
            AFC[mi], BFC[ni], acc[(MQ)*4 + mi][ni], 0, 0, 0);                 \
    __builtin_amdgcn_s_setprio(0);                                            \
    VMW_STMT;                                                                 \
    __builtin_amdgcn_s_barrier();                                             \
  }

template <int EPI>
__global__ __launch_bounds__(512, 2) void gemm256(
    const bf16_t* __restrict__ A, int lda,
    const bf16_t* __restrict__ B, int ldb,
    void* Cv, int ldc, const float* R, float* C2, int Ksp,
    int K, int Nt, float scale)
{
    int id = blockIdx.x;
    int xcd = id & 7, p = id >> 3;
    int chunk = gridDim.x >> 3;
    int g = xcd * chunk + p;
    int bm = g / Nt, bn = g % Nt;
    int sK = (EPI == 3) ? blockIdx.y : 0;

    __shared__ __align__(16) bf16_t As[2][2][256 * 32];
    __shared__ __align__(16) bf16_t Bs[2][2][256 * 32];

    int t = threadIdx.x;
    int w = t >> 6, l = t & 63;
    int wm = w >> 2, wn = w & 3;      // 2M x 4N waves
    int lm = l & 15, quad = l >> 4;

    const bf16_t* Ag = A + (size_t)(bm * 256) * lda + (size_t)sK * Ksp;
    const bf16_t* Bg = B + (size_t)(bn * 256) * ldb + (size_t)sK * Ksp;

    // staging: instr j covers chunk c = j*512 + w*64 + l; row = c>>2,
    // slot = c&3, source k-chunk g = slot ^ ((row>>1)&3) = (l&3)^((l>>3)&3)
    int g4 = ((l & 3) ^ ((l >> 3) & 3)) * 8;
    const bf16_t* rA0 = Ag + (size_t)(w * 16 + (l >> 2)) * lda + g4;
    const bf16_t* rA1 = rA0 + (size_t)128 * lda;
    const bf16_t* rB0 = Bg + (size_t)(w * 16 + (l >> 2)) * ldb + g4;
    const bf16_t* rB1 = rB0 + (size_t)128 * ldb;

    // ds_read: row = wm*128 + mq*64 + mi*16 + lm -> (row>>1)&3 = (lm>>1)&3;
    // elem = row*32 + (quad ^ ((lm>>1)&3))*8
    int slot8 = (quad ^ ((lm >> 1) & 3)) * 8;
    int arow = (wm * 128 + lm) * 32 + slot8;
    int brow = (wn * 64 + lm) * 32 + slot8;

    f32x4 acc[8][4] = {};
    bf16x8 af0[4], af1[4], bfr0[4], bfr1[4];

    // prologue: tile0 (k0,k1) + tile1 (k0) = 12 loads; vmcnt(8) -> tile0-k0
    // done; barrier publishes; then read ph1's fragments (b0,k0,mq0).
    STAGE_A(0, 0, 0);  STAGE_B(0, 0, 0);
    STAGE_A(0, 1, 32); STAGE_B(0, 1, 32);
    STAGE_A(1, 0, 64); STAGE_B(1, 0, 64);
    asm volatile("s_waitcnt vmcnt(8)" ::: "memory");
    __builtin_amdgcn_s_barrier();
    RD_A(af0, 0, 0, 0);
    RD_B(bfr0, 0, 0);

    int T = K >> 7;  // iterations of 2 K-tiles (K multiple of 128, T >= 2)
    for (int it = 0; it < T - 1; ++it) {
        int kb = it << 7;
        PHASE(af0, bfr0, 0, RD_A(af1, 0, 0, 1),                      4,
              STAGE_A(1, 1, kb + 96), VM6);                              // ph1
        PHASE(af1, bfr0, 1, { RD_A(af0, 0, 1, 0); RD_B(bfr1, 0, 1); }, 8,
              STAGE_B(1, 1, kb + 96), NOP);                              // ph2
        PHASE(af0, bfr1, 0, RD_A(af1, 0, 1, 1),                      4,
              STAGE_A(0, 0, kb + 128), VM6);                             // ph3
        PHASE(af1, bfr1, 1, { RD_A(af0, 1, 0, 0); RD_B(bfr0, 1, 0); }, 8,
              STAGE_B(0, 0, kb + 128), NOP);                             // ph4
        PHASE(af0, bfr0, 0, RD_A(af1, 1, 0, 1),                      4,
              STAGE_A(0, 1, kb + 160), VM6);                             // ph5
        PHASE(af1, bfr0, 1, { RD_A(af0, 1, 1, 0); RD_B(bfr1, 1, 1); }, 8,
              STAGE_B(0, 1, kb + 160), NOP);                             // ph6
        PHASE(af0, bfr1, 0, RD_A(af1, 1, 1, 1),                      4,
              STAGE_A(1, 0, kb + 192), VM6);                             // ph7
        PHASE(af1, bfr1, 1, { RD_A(af0, 0, 0, 0); RD_B(bfr0, 0, 0); }, 8,
              STAGE_B(1, 0, kb + 192), NOP);                             // ph8
    }
    {   // peeled last iteration: only b1k1 still needs staging; waits 6/4/0
        int kb = (T - 1) << 7;
        PHASE(af0, bfr0, 0, RD_A(af1, 0, 0, 1),                      4,
              STAGE_A(1, 1, kb + 96), VM6);
        PHASE(af1, bfr0, 1, { RD_A(af0, 0, 1, 0); RD_B(bfr1, 0, 1); }, 8,
              STAGE_B(1, 1, kb + 96), NOP);
        PHASE(af0, bfr1, 0, RD_A(af1, 0, 1, 1),                      4,
              NOP, VM4);
        PHASE(af1, bfr1, 1, { RD_A(af0, 1, 0, 0); RD_B(bfr0, 1, 0); }, 8,
              NOP, NOP);
        PHASE(af0, bfr0, 0, RD_A(af1, 1, 0, 1),                      4,
              NOP, VM0);
        PHASE(af1, bfr0, 1, { RD_A(af0, 1, 1, 0); RD_B(bfr1, 1, 1); }, 8,
              NOP, NOP);
        PHASE(af0, bfr1, 0, RD_A(af1, 1, 1, 1),                      4,
              NOP, NOP);
        PHASE(af1, bfr1, 1, NOP,                                     0,
              NOP, NOP);
    }

#pragma unroll
    for (int mq = 0; mq < 2; mq++) {
#pragma unroll
        for (int mi = 0; mi < 4; mi++) {
#pragma unroll
            for (int r = 0; r < 4; r++) {
                int row = bm * 256 + wm * 128 + mq * 64 + mi * 16 + quad * 4 + r;
#pragma unroll
                for (int ni = 0; ni < 4; ni++) {
                    int col = bn * 256 + wn * 64 + ni * 16 + lm;
                    float v = acc[mq * 4 + mi][ni][r];
                    size_t idx = (size_t)row * ldc + col;
                    if (EPI == 0) {
                        ((bf16_t*)Cv)[idx] = (bf16_t)(v * scale);
                    } else if (EPI == 1) {
                        float ge = 0.5f * v * (1.0f + erff(v * 0.70710678118654752f));
                        ((bf16_t*)Cv)[idx] = (bf16_t)ge;
                    } else if (EPI == 2) {
                        float rv = R[(size_t)row * ldc + col];
                        ((float*)Cv)[idx] = v + rv;
                    } else {  // 3: split-K
                        if (sK == 0) {
                            float rv = R[(size_t)row * ldc + col];
                            ((float*)Cv)[idx] = v + rv;
                        } else {
                            C2[idx] = v;
                        }
                    }
                }
            }
        }
    }
}

// ---------------------------------------------------------------------------
// Launch. fp32 I/O, bf16 internals.
// ws layout (MiB): [0,6) qkvb | [6,8) opT | [8,16) f1b | [16,24) f2b
//   [24,40) h1 -> VT -> h2 (disjoint lifetimes)
//   [40,88) QKVb; then AV [40,56); then G0:
//     bigws: G0 = [8192][4096] at [40,104)  (fused single ffn1+ffn2)
//     else : G0 = [8192][2048] at [40,72), two-half loop
//   [104,136) P1 (fp32 split-K partial for ffn2, only if ws >= 136 MiB)
// SP (bf16 32 MiB) lives in d_out (fp32, unused until out_proj).
// ---------------------------------------------------------------------------
extern "C" void kernel_launch(void* const* d_in, const int* in_sizes, int n_in,
                              void* d_out, int out_size, void* d_ws, size_t ws_size,
                              hipStream_t stream)
{
    (void)in_sizes; (void)n_in; (void)out_size;
    const float* x    = (const float*)d_in[0];
    const float* ln1  = (const float*)d_in[1];
    const float* ln2  = (const float*)d_in[2];
    const float* ffn1 = (const float*)d_in[3];
    const float* ffn2 = (const float*)d_in[4];
    const float* kp   = (const float*)d_in[5];
    const float* qp   = (const float*)d_in[6];
    const float* vp   = (const float*)d_in[7];
    const float* op   = (const float*)d_in[8];
    float* out = (float*)d_out;

    const size_t MiB = 1048576;
    char* ws = (char*)d_ws;
    bf16_t* qkvb = (bf16_t*)(ws + 0 * MiB);
    bf16_t* opT  = (bf16_t*)(ws + 6 * MiB);
    bf16_t* f1b  = (bf16_t*)(ws + 8 * MiB);
    bf16_t* f2b  = (bf16_t*)(ws + 16 * MiB);
    bf16_t* h1   = (bf16_t*)(ws + 24 * MiB);
    bf16_t* VT   = (bf16_t*)(ws + 24 * MiB);  // h1 dead after QKV gemm
    bf16_t* h2   = (bf16_t*)(ws + 24 * MiB);  // VT dead after AV gemm
    bf16_t* QKVb = (bf16_t*)(ws + 40 * MiB);  // [8192][3072]
    bf16_t* AV   = (bf16_t*)(ws + 40 * MiB);  // QKVb dead after V^T
    bf16_t* G0   = (bf16_t*)(ws + 40 * MiB);  // AV dead after out_proj
    float*  P1   = (float*)(ws + 104 * MiB);  // split-K partial
    bf16_t* SP   = (bf16_t*)d_out;
    bool bigws  = ws_size >= 104 * MiB;
    bool splitw = ws_size >= 136 * MiB;

    dim3 blk(256);
    dim3 blk5(512);
    const int HUGE_K = 1 << 30;

    // 1) prep: weight cvt + out_proj^T + rmsnorm1
    prep_kernel<<<dim3(20480), blk, 0, stream>>>(
        qp, kp, vp, ffn1, ffn2, op, x, ln1, qkvb, f1b, f2b, opT, h1);

    // 2) fused QKV: [8192,1024] x [3072,1024]^T -> QKVb  (384 blocks)
    gemm256<0><<<dim3(384), blk5, 0, stream>>>(
        h1, 1024, qkvb, 1024, QKVb, 3072, nullptr, nullptr, 0, 1024, 12, 1.0f);

    // 3) scores = Q K^T / 32, lower-triangular tiles -> SP (in d_out)
    gemm_bt<0, true, false, false><<<dim3(256, 1, 4), blk, 0, stream>>>(
        QKVb, QKVb, 3072, QKVb + 1024, 3072, SP, 2048, nullptr,
        1024, HUGE_K, 16,
        (long long)2048 * 3072, (long long)2048 * 3072, (long long)2048 * 2048,
        1.0f / 32.0f);

    // 4) V -> V^T per batch (V = QKVb cols [2048,3072); VT into h1 slot)
    transpose_bf16<<<dim3(32, 64, 4), blk, 0, stream>>>(
        QKVb + 2048, VT, 2048, 3072,
        (long long)2048 * 3072, (long long)1024 * 2048);

    // 5) causal softmax in place (vectorized, causal-skip)
    causal_softmax_kernel<<<dim3(2048, 4), blk, 0, stream>>>(SP);

    // 6) AV = P @ V (B = V^T [1024][2048], causal K clamp)
    gemm_bt<0, false, true, false><<<dim3(128, 1, 4), blk, 0, stream>>>(
        SP, SP, 2048, VT, 2048, AV, 1024, nullptr,
        2048, HUGE_K, 16,
        (long long)2048 * 2048, (long long)1024 * 2048, (long long)2048 * 1024,
        1.0f);

    // 7) out = x + AV @ out_proj^T  (128 blocks; SP dead)
    gemm256<2><<<dim3(128), blk5, 0, stream>>>(
        AV, 1024, opT, 1024, out, 1024, x, nullptr, 0, 1024, 4, 1.0f);

    // 8) h2 = rmsnorm(x) * ln2
    rmsnorm_kernel<<<dim3(8192), blk, 0, stream>>>(x, ln2, h2);

    if (bigws) {
        // 9) G0 = gelu(h2 @ ffn1^T), single fused [8192][4096] (512 blocks)
        gemm256<1><<<dim3(512), blk5, 0, stream>>>(
            h2, 1024, f1b, 1024, G0, 4096, nullptr, nullptr, 0, 1024, 16, 1.0f);
        if (splitw) {
            // 10) split-K=2: s0 -> out = v0 + out, s1 -> P1 = v1; then combine
            gemm256<3><<<dim3(128, 2), blk5, 0, stream>>>(
                G0, 4096, f2b, 4096, out, 1024, out, P1, 2048, 2048, 4, 1.0f);
            addp_kernel<<<dim3(2048), blk, 0, stream>>>(out, P1, 2097152);
        } else {
            gemm256<2><<<dim3(128), blk5, 0, stream>>>(
                G0, 4096, f2b, 4096, out, 1024, out, nullptr, 0, 4096, 4, 1.0f);
        }
    } else {
        for (int half = 0; half < 2; half++) {
            gemm_bt<1, false, false, false><<<dim3(1024), blk, 0, stream>>>(
                h2, h2, 1024, f1b + (size_t)half * 2048 * 1024, 1024, G0, 2048,
                nullptr, 1024, HUGE_K, 64, 0, 0, 0, 1.0f);
            gemm_bt<2, false, false, false><<<dim3(512), blk, 0, stream>>>(
                G0, G0, 2048, f2b + half * 2048, 4096, out, 1024, out,
                2048, HUGE_K, 64, 0, 0, 0, 1.0f);
        }
    }
}

// Round 7
// 520.946 us; speedup vs baseline: 1.1231x; 1.1231x over previous
//
#include <hip/hip_runtime.h>
#include <math.h>

typedef __bf16 bf16_t;
typedef __bf16 bf16x8 __attribute__((ext_vector_type(8)));
typedef float f32x4 __attribute__((ext_vector_type(4)));

// async global->LDS, 16B per lane; LDS dest is wave-uniform base + lane*16
#define LDS16(g, l) __builtin_amdgcn_global_load_lds( \
    (__attribute__((address_space(1))) void*)(g),     \
    (__attribute__((address_space(3))) void*)(l), 16, 0, 0)

// ---------------------------------------------------------------------------
// Prep kernel: blocks [0,11264) fp32->bf16 flat weight cvt;
// [11264,12288) out_proj^T (32x32 tiles); [12288,20480) rmsnorm rows:
// one reduction per row, writes BOTH h1 = x*rinv*ln1 and (if h2p) h2 =
// x*rinv*ln2 (same rms!) -- folds the old rmsnorm_kernel into prep.
// ---------------------------------------------------------------------------
__global__ __launch_bounds__(256) void prep_kernel(
    const float* __restrict__ qp, const float* __restrict__ kp,
    const float* __restrict__ vp, const float* __restrict__ f1,
    const float* __restrict__ f2, const float* __restrict__ op,
    const float* __restrict__ x, const float* __restrict__ ln1,
    const float* __restrict__ ln2,
    bf16_t* __restrict__ qkvb, bf16_t* __restrict__ f1b,
    bf16_t* __restrict__ f2b, bf16_t* __restrict__ opT,
    bf16_t* __restrict__ h1, bf16_t* h2p)
{
    __shared__ float tile[32][33];
    __shared__ float red[4];
    int bid = blockIdx.x;
    int t = threadIdx.x;
    if (bid < 11264) {
        size_t i = ((size_t)bid * 256 + t) * 4;
        const float* src;
        bf16_t* dst;
        if (i < 3145728) {
            if (i < 1048576)      { src = qp + i;             dst = qkvb + i; }
            else if (i < 2097152) { src = kp + (i - 1048576); dst = qkvb + i; }
            else                  { src = vp + (i - 2097152); dst = qkvb + i; }
        } else if (i < 7340032) { src = f1 + (i - 3145728); dst = f1b + (i - 3145728); }
        else                    { src = f2 + (i - 7340032); dst = f2b + (i - 7340032); }
        float4 v = *(const float4*)src;
        dst[0] = (bf16_t)v.x; dst[1] = (bf16_t)v.y;
        dst[2] = (bf16_t)v.z; dst[3] = (bf16_t)v.w;
    } else if (bid < 12288) {
        int b2 = bid - 11264;
        int c0 = (b2 & 31) * 32, r0 = (b2 >> 5) * 32;
        int tx = t & 31, ty = t >> 5;  // 32 x 8
#pragma unroll
        for (int i = 0; i < 32; i += 8)
            tile[ty + i][tx] = op[(size_t)(r0 + ty + i) * 1024 + c0 + tx];
        __syncthreads();
#pragma unroll
        for (int i = 0; i < 32; i += 8)
            opT[(size_t)(c0 + ty + i) * 1024 + r0 + tx] = (bf16_t)tile[tx][ty + i];
    } else {
        int row = bid - 12288;
        float4 xv = ((const float4*)(x + (size_t)row * 1024))[t];
        float ss = xv.x * xv.x + xv.y * xv.y + xv.z * xv.z + xv.w * xv.w;
#pragma unroll
        for (int o = 32; o > 0; o >>= 1) ss += __shfl_xor(ss, o, 64);
        if ((t & 63) == 0) red[t >> 6] = ss;
        __syncthreads();
        ss = red[0] + red[1] + red[2] + red[3];
        float rinv = rsqrtf(ss * (1.0f / 1024.0f) + 1e-5f);
        float4 w1 = ((const float4*)ln1)[t];
        bf16_t* hp = h1 + (size_t)row * 1024 + t * 4;
        hp[0] = (bf16_t)(xv.x * rinv * w1.x);
        hp[1] = (bf16_t)(xv.y * rinv * w1.y);
        hp[2] = (bf16_t)(xv.z * rinv * w1.z);
        hp[3] = (bf16_t)(xv.w * rinv * w1.w);
        if (h2p) {
            float4 w2 = ((const float4*)ln2)[t];
            bf16_t* hq = h2p + (size_t)row * 1024 + t * 4;
            hq[0] = (bf16_t)(xv.x * rinv * w2.x);
            hq[1] = (bf16_t)(xv.y * rinv * w2.y);
            hq[2] = (bf16_t)(xv.z * rinv * w2.z);
            hq[3] = (bf16_t)(xv.w * rinv * w2.w);
        }
    }
}

// ---------------------------------------------------------------------------
// RMSNorm standalone (small-ws fallback only)
// ---------------------------------------------------------------------------
__global__ __launch_bounds__(256) void rmsnorm_kernel(
    const float* __restrict__ x, const float* __restrict__ w,
    bf16_t* __restrict__ h)
{
    int row = blockIdx.x;
    int t = threadIdx.x;
    float4 xv = ((const float4*)(x + (size_t)row * 1024))[t];
    float ss = xv.x * xv.x + xv.y * xv.y + xv.z * xv.z + xv.w * xv.w;
#pragma unroll
    for (int o = 32; o > 0; o >>= 1) ss += __shfl_xor(ss, o, 64);
    __shared__ float red[4];
    if ((t & 63) == 0) red[t >> 6] = ss;
    __syncthreads();
    ss = red[0] + red[1] + red[2] + red[3];
    float rinv = rsqrtf(ss * (1.0f / 1024.0f) + 1e-5f);
    float4 wv = ((const float4*)w)[t];
    bf16_t* hp = h + (size_t)row * 1024 + t * 4;
    hp[0] = (bf16_t)(xv.x * rinv * wv.x);
    hp[1] = (bf16_t)(xv.y * rinv * wv.y);
    hp[2] = (bf16_t)(xv.z * rinv * wv.z);
    hp[3] = (bf16_t)(xv.w * rinv * wv.w);
}

// ---------------------------------------------------------------------------
// bf16 batched transpose with input row stride: out[c][r] = in[r*ldin + c]
// ---------------------------------------------------------------------------
__global__ __launch_bounds__(256) void transpose_bf16(
    const bf16_t* __restrict__ in, bf16_t* __restrict__ out,
    int rows, int ldin, long long sIn, long long sOut)
{
    __shared__ bf16_t tile[32][33];
    int b = blockIdx.z;
    const bf16_t* ip = in + (long long)b * sIn;
    bf16_t* op = out + (long long)b * sOut;
    int c0 = blockIdx.x * 32, r0 = blockIdx.y * 32;
    int tx = threadIdx.x & 31, ty = threadIdx.x >> 5;
#pragma unroll
    for (int i = 0; i < 32; i += 8)
        tile[ty + i][tx] = ip[(size_t)(r0 + ty + i) * ldin + c0 + tx];
    __syncthreads();
#pragma unroll
    for (int i = 0; i < 32; i += 8)
        op[(size_t)(c0 + ty + i) * rows + r0 + tx] = tile[tx][ty + i];
}

// ---------------------------------------------------------------------------
// Causal softmax, in place, vectorized (__expf; softmax renormalizes so the
// ~1e-5 rel error is harmless). Row q: softmax over cols [0,q]; writes zeros
// on (q, Jstore) where Jstore = next 128-boundary (AV-gemm K-clamp bound).
// ---------------------------------------------------------------------------
__global__ __launch_bounds__(256) void causal_softmax_kernel(bf16_t* __restrict__ SP)
{
    const int S = 2048;
    int q = blockIdx.x, b = blockIdx.y;
    bf16_t* row = SP + ((size_t)b * S + q) * S;
    int t = threadIdx.x;
    int j0 = t * 8;
    int Jstore = ((q >> 7) + 1) << 7;

    float v[8];
    if (j0 + 7 <= q) {
        bf16x8 xv = *(const bf16x8*)(row + j0);
#pragma unroll
        for (int i = 0; i < 8; i++) v[i] = (float)xv[i];
    } else if (j0 <= q) {
#pragma unroll
        for (int i = 0; i < 8; i++)
            v[i] = (j0 + i <= q) ? (float)row[j0 + i] : -1e30f;
    } else {
#pragma unroll
        for (int i = 0; i < 8; i++) v[i] = -1e30f;
    }

    float mx = v[0];
#pragma unroll
    for (int i = 1; i < 8; i++) mx = fmaxf(mx, v[i]);
#pragma unroll
    for (int o = 32; o > 0; o >>= 1) mx = fmaxf(mx, __shfl_xor(mx, o, 64));
    __shared__ float sm[4], ssum[4];
    if ((t & 63) == 0) sm[t >> 6] = mx;
    __syncthreads();
    mx = fmaxf(fmaxf(sm[0], sm[1]), fmaxf(sm[2], sm[3]));

    float e[8];
    float sum = 0.f;
#pragma unroll
    for (int i = 0; i < 8; i++) {
        e[i] = (v[i] > -1e29f) ? __expf(v[i] - mx) : 0.f;
        sum += e[i];
    }
#pragma unroll
    for (int o = 32; o > 0; o >>= 1) sum += __shfl_xor(sum, o, 64);
    if ((t & 63) == 0) ssum[t >> 6] = sum;
    __syncthreads();
    sum = ssum[0] + ssum[1] + ssum[2] + ssum[3];
    float r = 1.0f / sum;

    if (j0 < Jstore) {
        bf16x8 ov;
#pragma unroll
        for (int i = 0; i < 8; i++) ov[i] = (bf16_t)(e[i] * r);
        *(bf16x8*)(row + j0) = ov;
    }
}

// ---------------------------------------------------------------------------
// MFMA GEMM (128x128, 2-barrier, 32 KiB LDS -> multi-block/CU): workhorse
// for QKV / scores (CSKIP) / AV (CKLOOP) / out_proj / ffn2 + smallws path.
// ---------------------------------------------------------------------------
template <int EPI, bool CSKIP, bool CKLOOP, bool ASPLIT>
__global__ __launch_bounds__(256) void gemm_bt(
    const bf16_t* __restrict__ A, const bf16_t* __restrict__ A2, int lda,
    const bf16_t* __restrict__ B, int ldb,
    void* Cv, int ldc, const float* R,
    int K, int Ksp, int Mt, long long sA, long long sB, long long sC,
    float scale)
{
    int id = blockIdx.x, bz = blockIdx.z;
    int xcd = id & 7, p = id >> 3;
    int chunk = Mt >> 3;
    int bm = xcd * chunk + (p % chunk);
    int bn = p / chunk;
    if (CSKIP && bn > bm) return;

    __shared__ __align__(16) bf16_t At[128 * 64];
    __shared__ __align__(16) bf16_t Bt[128 * 64];
    int t = threadIdx.x;
    int w = t >> 6, l = t & 63;
    int wm = w >> 1, wn = w & 1;
    int lane_m = l & 15, quad = l >> 4;

    const bf16_t* Ag = A + (long long)bz * sA + (size_t)(bm * 128) * lda;
    const bf16_t* Bg = B + (long long)bz * sB + (size_t)(bn * 128) * ldb;

    int Keff = K;
    if (CKLOOP) {
        int kk = (bm + 1) * 128;
        if (kk < K) Keff = kk;
    }

    f32x4 acc[4][4] = {};

    int rb = w * 8 + (l >> 3);
    int g0 = ((l & 7) ^ ((l >> 3) & 7)) * 8;
    const bf16_t* a0[4];
    const bf16_t* a1[4];
    const bf16_t* b0[4];
#pragma unroll
    for (int j = 0; j < 4; j++) {
        size_t ro = (size_t)(rb + 32 * j);
        a0[j] = Ag + ro * lda + g0;
        if (ASPLIT) a1[j] = A2 + (long long)bz * sA + (size_t)(bm * 128) * lda
                           + ro * lda + g0;
        b0[j] = Bg + ro * ldb + g0;
    }

    int s0 = (quad ^ (lane_m & 7)) * 8;        // k-half 0: g = quad
    int s1 = ((4 + quad) ^ (lane_m & 7)) * 8;  // k-half 1: g = 4+quad

    for (int kt = 0; kt < Keff; kt += 64) {
        __syncthreads();
#pragma unroll
        for (int j = 0; j < 4; j++) {
            const bf16_t* pa = a0[j] + kt;
            if (ASPLIT && kt >= Ksp) pa = a1[j] + (kt - Ksp);
            LDS16(pa, At + (size_t)w * 512 + j * 2048);
            LDS16(b0[j] + kt, Bt + (size_t)w * 512 + j * 2048);
        }
        __syncthreads();

#pragma unroll
        for (int h = 0; h < 2; h++) {
            int sh = h ? s1 : s0;
            bf16x8 af[4], bfr[4];
#pragma unroll
            for (int mi = 0; mi < 4; mi++)
                af[mi] = *(const bf16x8*)(At + (wm * 64 + mi * 16 + lane_m) * 64 + sh);
#pragma unroll
            for (int ni = 0; ni < 4; ni++)
                bfr[ni] = *(const bf16x8*)(Bt + (wn * 64 + ni * 16 + lane_m) * 64 + sh);
#pragma unroll
            for (int mi = 0; mi < 4; mi++)
#pragma unroll
                for (int ni = 0; ni < 4; ni++)
                    acc[mi][ni] = __builtin_amdgcn_mfma_f32_16x16x32_bf16(
                        af[mi], bfr[ni], acc[mi][ni], 0, 0, 0);
        }
    }

    long long cbase = (long long)bz * sC;
#pragma unroll
    for (int mi = 0; mi < 4; mi++) {
#pragma unroll
        for (int r = 0; r < 4; r++) {
            int row = bm * 128 + wm * 64 + mi * 16 + quad * 4 + r;
#pragma unroll
            for (int ni = 0; ni < 4; ni++) {
                int col = bn * 128 + wn * 64 + ni * 16 + lane_m;
                float v = acc[mi][ni][r];
                size_t idx = (size_t)(cbase + (long long)row * ldc + col);
                if (EPI == 0) {
                    ((bf16_t*)Cv)[idx] = (bf16_t)(v * scale);
                } else if (EPI == 1) {
                    float g = 0.5f * v * (1.0f + erff(v * 0.70710678118654752f));
                    ((bf16_t*)Cv)[idx] = (bf16_t)g;
                } else {
                    float rv = R[(size_t)row * ldc + col];
                    ((float*)Cv)[idx] = v + rv;
                }
            }
        }
    }
}

// ---------------------------------------------------------------------------
// gemm256 (r5-verified: conflicts=0, 99 us on ffn1): 8-phase GEMM,
// BM=BN=256, BK=64, 512 thr = 8 waves (2M x 4N), wave tile 128x64.
// LDS 128 KiB: As/Bs[buf][khalf][256 rows][4 slots x 8].
// Swizzle: slot = g ^ ((row>>1)&3)  (bank-quad = 4*(lm&1) + (quad^((lm>>1)&3)),
// disjoint bits -> conflict-free). Used where it measured best: ffn1 (N=4096,
// 512 blocks = 2 clean passes). 2-barrier phases + VM8 counted waits.
// ---------------------------------------------------------------------------
#define VM8 asm volatile("s_waitcnt vmcnt(8)" ::: "memory")
#define VM4 asm volatile("s_waitcnt vmcnt(4)" ::: "memory")
#define VM0 asm volatile("s_waitcnt vmcnt(0)" ::: "memory")
#define NOP ((void)0)

#define STAGE_A(BUF, KH, KOFF) do { \
    LDS16(rA0 + (KOFF), &As[BUF][KH][w * 512]);        \
    LDS16(rA1 + (KOFF), &As[BUF][KH][4096 + w * 512]); } while (0)
#define STAGE_B(BUF, KH, KOFF) do { \
    LDS16(rB0 + (KOFF), &Bs[BUF][KH][w * 512]);        \
    LDS16(rB1 + (KOFF), &Bs[BUF][KH][4096 + w * 512]); } while (0)

#define PHASE(BUF, KH, MQ, STAGE_STMT, WAIT_STMT)                             \
  {                                                                           \
    _Pragma("unroll") for (int mi = 0; mi < 4; mi++)                          \
        af[mi] = *(const bf16x8*)&As[BUF][KH][arow + (MQ)*2048 + mi*512];     \
    if ((MQ) == 0) {                                                          \
      _Pragma("unroll") for (int ni = 0; ni < 4; ni++)                        \
          bfr[ni] = *(const bf16x8*)&Bs[BUF][KH][brow + ni*512];              \
    }                                                                         \
    STAGE_STMT;                                                               \
    __builtin_amdgcn_s_barrier();                                             \
    asm volatile("s_waitcnt lgkmcnt(0)" ::: "memory");                        \
    __builtin_amdgcn_sched_barrier(0);                                        \
    __builtin_amdgcn_s_setprio(1);                                            \
    _Pragma("unroll") for (int mi = 0; mi < 4; mi++)                          \
      _Pragma("unroll") for (int ni = 0; ni < 4; ni++)                        \
        acc[(MQ)*4 + mi][ni] = __builtin_amdgcn_mfma_f32_16x16x32_bf16(       \
            af[mi], bfr[ni], acc[(MQ)*4 + mi][ni], 0, 0, 0);                  \
    __builtin_amdgcn_s_setprio(0);                                            \
    WAIT_STMT;                                                                \
    __builtin_amdgcn_s_barrier();                                             \
  }

template <int EPI>
__global__ __launch_bounds__(512, 2) void gemm256(
    const bf16_t* __restrict__ A, int lda,
    const bf16_t* __restrict__ B, int ldb,
    void* Cv, int ldc, const float* R, int K, int Nt, float scale)
{
    int id = blockIdx.x;
    int xcd = id & 7, p = id >> 3;
    int chunk = gridDim.x >> 3;
    int g = xcd * chunk + p;
    int bm = g / Nt, bn = g % Nt;

    __shared__ __align__(16) bf16_t As[2][2][256 * 32];
    __shared__ __align__(16) bf16_t Bs[2][2][256 * 32];

    int t = threadIdx.x;
    int w = t >> 6, l = t & 63;
    int wm = w >> 2, wn = w & 3;      // 2M x 4N waves
    int lm = l & 15, quad = l >> 4;

    const bf16_t* Ag = A + (size_t)(bm * 256) * lda;
    const bf16_t* Bg = B + (size_t)(bn * 256) * ldb;

    int g4 = ((l & 3) ^ ((l >> 3) & 3)) * 8;
    const bf16_t* rA0 = Ag + (size_t)(w * 16 + (l >> 2)) * lda + g4;
    const bf16_t* rA1 = rA0 + (size_t)128 * lda;
    const bf16_t* rB0 = Bg + (size_t)(w * 16 + (l >> 2)) * ldb + g4;
    const bf16_t* rB1 = rB0 + (size_t)128 * ldb;

    int slot8 = (quad ^ ((lm >> 1) & 3)) * 8;
    int arow = (wm * 128 + lm) * 32 + slot8;
    int brow = (wn * 64 + lm) * 32 + slot8;

    f32x4 acc[8][4] = {};
    bf16x8 af[4], bfr[4];

    // prologue: tile0 (k0,k1) + tile1 (k0) = 12 loads; vmcnt(8) -> tile0-k0 done
    STAGE_A(0, 0, 0);  STAGE_B(0, 0, 0);
    STAGE_A(0, 1, 32); STAGE_B(0, 1, 32);
    STAGE_A(1, 0, 64); STAGE_B(1, 0, 64);
    VM8;
    __builtin_amdgcn_s_barrier();

    int T = K >> 7;  // iterations of 2 K-tiles (K multiple of 128, T >= 2)
    for (int it = 0; it < T - 1; ++it) {
        int kb = it << 7;
        PHASE(0, 0, 0, STAGE_A(1, 1, kb + 96),  NOP);  // ph1
        PHASE(0, 0, 1, STAGE_B(1, 1, kb + 96),  VM8);  // ph2
        PHASE(0, 1, 0, STAGE_A(0, 0, kb + 128), NOP);  // ph3
        PHASE(0, 1, 1, STAGE_B(0, 0, kb + 128), VM8);  // ph4
        PHASE(1, 0, 0, STAGE_A(0, 1, kb + 160), NOP);  // ph5
        PHASE(1, 0, 1, STAGE_B(0, 1, kb + 160), VM8);  // ph6
        PHASE(1, 1, 0, STAGE_A(1, 0, kb + 192), NOP);  // ph7
        PHASE(1, 1, 1, STAGE_B(1, 0, kb + 192), VM8);  // ph8
    }
    {   // peeled last iteration
        int kb = (T - 1) << 7;
        PHASE(0, 0, 0, STAGE_A(1, 1, kb + 96), NOP);
        PHASE(0, 0, 1, STAGE_B(1, 1, kb + 96), VM8);
        PHASE(0, 1, 0, NOP, NOP);
        PHASE(0, 1, 1, NOP, VM4);
        PHASE(1, 0, 0, NOP, NOP);
        PHASE(1, 0, 1, NOP, VM0);
        PHASE(1, 1, 0, NOP, NOP);
        PHASE(1, 1, 1, NOP, NOP);
    }

#pragma unroll
    for (int mq = 0; mq < 2; mq++) {
#pragma unroll
        for (int mi = 0; mi < 4; mi++) {
#pragma unroll
            for (int r = 0; r < 4; r++) {
                int row = bm * 256 + wm * 128 + mq * 64 + mi * 16 + quad * 4 + r;
#pragma unroll
                for (int ni = 0; ni < 4; ni++) {
                    int col = bn * 256 + wn * 64 + ni * 16 + lm;
                    float v = acc[mq * 4 + mi][ni][r];
                    size_t idx = (size_t)row * ldc + col;
                    if (EPI == 0) {
                        ((bf16_t*)Cv)[idx] = (bf16_t)(v * scale);
                    } else if (EPI == 1) {
                        float ge = 0.5f * v * (1.0f + erff(v * 0.70710678118654752f));
                        ((bf16_t*)Cv)[idx] = (bf16_t)ge;
                    } else {
                        float rv = R[(size_t)row * ldc + col];
                        ((float*)Cv)[idx] = v + rv;
                    }
                }
            }
        }
    }
}

// ---------------------------------------------------------------------------
// Launch. fp32 I/O, bf16 internals. Best-measured config per GEMM:
//   QKV / scores / AV / out_proj / ffn2 -> gemm_bt (multi-block/CU grids)
//   ffn1 (N=4096 fused) -> gemm256 (512 blocks; measured 99us vs 116)
// ws layout, bigws (>=104 MiB):
//   [0,6) qkvb | [6,8) opT | [8,16) f1b | [16,24) f2b
//   [24,40) h1 -> VT (transpose) ; [40,88) QKVb -> AV [40,56)
//   [88,104) h2 (written by prep, lives until ffn1)
//   [24,88) G0 [8192][4096] (h1/VT/AV dead by ffn1 time)
// SP (bf16 32 MiB) lives in d_out (unused until out_proj).
// ---------------------------------------------------------------------------
extern "C" void kernel_launch(void* const* d_in, const int* in_sizes, int n_in,
                              void* d_out, int out_size, void* d_ws, size_t ws_size,
                              hipStream_t stream)
{
    (void)in_sizes; (void)n_in; (void)out_size;
    const float* x    = (const float*)d_in[0];
    const float* ln1  = (const float*)d_in[1];
    const float* ln2  = (const float*)d_in[2];
    const float* ffn1 = (const float*)d_in[3];
    const float* ffn2 = (const float*)d_in[4];
    const float* kp   = (const float*)d_in[5];
    const float* qp   = (const float*)d_in[6];
    const float* vp   = (const float*)d_in[7];
    const float* op   = (const float*)d_in[8];
    float* out = (float*)d_out;

    const size_t MiB = 1048576;
    char* ws = (char*)d_ws;
    bf16_t* qkvb = (bf16_t*)(ws + 0 * MiB);
    bf16_t* opT  = (bf16_t*)(ws + 6 * MiB);
    bf16_t* f1b  = (bf16_t*)(ws + 8 * MiB);
    bf16_t* f2b  = (bf16_t*)(ws + 16 * MiB);
    bf16_t* h1   = (bf16_t*)(ws + 24 * MiB);
    bf16_t* VT   = (bf16_t*)(ws + 24 * MiB);  // h1 dead after QKV gemm
    bf16_t* QKVb = (bf16_t*)(ws + 40 * MiB);  // [8192][3072]
    bf16_t* AV   = (bf16_t*)(ws + 40 * MiB);  // QKVb dead after V^T + scores
    bf16_t* h2   = (bf16_t*)(ws + 88 * MiB);  // bigws: written by prep
    bf16_t* G0   = (bf16_t*)(ws + 24 * MiB);  // [8192][4096]; VT/AV dead
    bf16_t* SP   = (bf16_t*)d_out;
    bool bigws = ws_size >= 104 * MiB;

    dim3 blk(256);
    dim3 blk5(512);
    const int HUGE_K = 1 << 30;

    // 1) prep: weight cvt + out_proj^T + rmsnorm rows (h1, and h2 if bigws)
    prep_kernel<<<dim3(20480), blk, 0, stream>>>(
        qp, kp, vp, ffn1, ffn2, op, x, ln1, ln2,
        qkvb, f1b, f2b, opT, h1, bigws ? h2 : (bf16_t*)nullptr);

    // 2) fused QKV: [8192,1024] x [3072,1024]^T -> QKVb  (1536 blocks, 4/CU)
    gemm_bt<0, false, false, false><<<dim3(1536), blk, 0, stream>>>(
        h1, h1, 1024, qkvb, 1024, QKVb, 3072, nullptr,
        1024, HUGE_K, 64, 0, 0, 0, 1.0f);

    // 3) scores = Q K^T / 32, lower-triangular tiles -> SP (in d_out)
    gemm_bt<0, true, false, false><<<dim3(256, 1, 4), blk, 0, stream>>>(
        QKVb, QKVb, 3072, QKVb + 1024, 3072, SP, 2048, nullptr,
        1024, HUGE_K, 16,
        (long long)2048 * 3072, (long long)2048 * 3072, (long long)2048 * 2048,
        1.0f / 32.0f);

    // 4) V -> V^T per batch (V = QKVb cols [2048,3072); VT into h1 slot)
    transpose_bf16<<<dim3(32, 64, 4), blk, 0, stream>>>(
        QKVb + 2048, VT, 2048, 3072,
        (long long)2048 * 3072, (long long)1024 * 2048);

    // 5) causal softmax in place (vectorized, causal-skip, __expf)
    causal_softmax_kernel<<<dim3(2048, 4), blk, 0, stream>>>(SP);

    // 6) AV = P @ V (B = V^T [1024][2048], causal K clamp)
    gemm_bt<0, false, true, false><<<dim3(128, 1, 4), blk, 0, stream>>>(
        SP, SP, 2048, VT, 2048, AV, 1024, nullptr,
        2048, HUGE_K, 16,
        (long long)2048 * 2048, (long long)1024 * 2048, (long long)2048 * 1024,
        1.0f);

    // 7) out = x + AV @ out_proj^T  (512 blocks; SP dead after this)
    gemm_bt<2, false, false, false><<<dim3(512), blk, 0, stream>>>(
        AV, AV, 1024, opT, 1024, out, 1024, x,
        1024, HUGE_K, 64, 0, 0, 0, 1.0f);

    if (bigws) {
        // 8) G0 = gelu(h2 @ ffn1^T), fused [8192][4096] (gemm256, 512 blocks)
        gemm256<1><<<dim3(512), blk5, 0, stream>>>(
            h2, 1024, f1b, 1024, G0, 4096, nullptr, 1024, 16, 1.0f);
        // 9) out += G0 @ ffn2^T, single K=4096 pass (512 blocks, contiguous G0)
        gemm_bt<2, false, false, false><<<dim3(512), blk, 0, stream>>>(
            G0, G0, 4096, f2b, 4096, out, 1024, out,
            4096, HUGE_K, 64, 0, 0, 0, 1.0f);
    } else {
        // fallback: h2 into h1 slot (AV dead), two-half FFN via gemm_bt
        bf16_t* h2s = (bf16_t*)(ws + 24 * MiB);
        bf16_t* G0s = (bf16_t*)(ws + 40 * MiB);
        rmsnorm_kernel<<<dim3(8192), blk, 0, stream>>>(x, ln2, h2s);
        for (int half = 0; half < 2; half++) {
            gemm_bt<1, false, false, false><<<dim3(1024), blk, 0, stream>>>(
                h2s, h2s, 1024, f1b + (size_t)half * 2048 * 1024, 1024, G0s, 2048,
                nullptr, 1024, HUGE_K, 64, 0, 0, 0, 1.0f);
            gemm_bt<2, false, false, false><<<dim3(512), blk, 0, stream>>>(
                G0s, G0s, 2048, f2b + half * 2048, 4096, out, 1024, out,
                2048, HUGE_K, 64, 0, 0, 0, 1.0f);
        }
    }
}